// Round 9
// baseline (829.933 us; speedup 1.0000x reference)
//
#include <hip/hip_runtime.h>
#include <cstdint>
#include <cstddef>

#define M_DIM 4096
#define N_DIM 8192
#define K_DIM 4096

typedef __attribute__((ext_vector_type(4))) int int4v;

// ---------------------------------------------------------------------------
// Pack into MFMA-fragment order (int32 -> int8). R3-verified, byte-identical.
// p = 16-row panel, s = 64-byte kstep, lane l: chunk(p,s) is 1024 B where
// lane l holds row 16p+(l&15), k-bytes s*64 + (l>>4)*16 .. +16.
// ---------------------------------------------------------------------------
__global__ void __launch_bounds__(256) pack_frag(const int* __restrict__ a,
                                                 const int* __restrict__ b,
                                                 unsigned char* __restrict__ pa,
                                                 unsigned char* __restrict__ pb) {
    size_t t = (size_t)blockIdx.x * 256 + threadIdx.x;
    const size_t NA = (size_t)(M_DIM / 16) * (K_DIM / 64) * 64;
    const int* __restrict__ src;
    unsigned char* __restrict__ dst;
    if (t < NA) {
        src = a; dst = pa;
    } else {
        src = b; dst = pb; t -= NA;
    }
    const int l = (int)(t & 63);
    const int s = (int)((t >> 6) & 63);
    const int p = (int)(t >> 12);
    const int* g = src + ((size_t)(16 * p + (l & 15))) * K_DIM + s * 64 + (l >> 4) * 16;
    const int4v* g4 = (const int4v*)g;
    int4v o;
#pragma unroll
    for (int q = 0; q < 4; ++q) {
        int4v v = g4[q];
        o[q] = (v[0] & 0xff) | ((v[1] & 0xff) << 8) | ((v[2] & 0xff) << 16) | (v[3] << 24);
    }
    ((int4v*)dst)[t] = o;
}

// ---------------------------------------------------------------------------
// GEMM: block 256x256, 256 thr = 4 waves at 1 wave/SIMD, wave tile 128x128
// (8 A x 8 B panels, 64 MFMA/iter, acc 8x8). mfma_i32_16x16x64_i8.
// KEY vs R8: at 1 wave/SIMD the 512-VGPR budget holds TWO fragment register
// sets; iter T issues ds_reads of T+1's fragments into the alternate set
// before running T's 64 MFMAs (no dependency between them), so the LDS
// pipe services reads UNDER the MFMA burst instead of lockstep-serial.
// LDS quad-buffered (4 x 32 KB = 128 KB); staging issued 2 iters ahead;
// barrier per iter drains prefetches that are >=1300 cy old.
// ---------------------------------------------------------------------------
__device__ inline void async_copy16(const unsigned char* g, unsigned char* l) {
    __builtin_amdgcn_global_load_lds(
        (const __attribute__((address_space(1))) void*)g,
        (__attribute__((address_space(3))) void*)l,
        16, 0, 0);
}

__global__ void __launch_bounds__(256, 1) gemm_i8(const unsigned char* __restrict__ Ap,
                                                  const unsigned char* __restrict__ Bp,
                                                  const _Float16* __restrict__ arow,
                                                  const _Float16* __restrict__ acol,
                                                  _Float16* __restrict__ Cout) {
    __shared__ __align__(16) unsigned char As[4 * 16384];
    __shared__ __align__(16) unsigned char Bs[4 * 16384];

    const int tid  = threadIdx.x;
    const int lane = tid & 63;
    const int wave = tid >> 6;        // 0..3
    const int bn   = blockIdx.x;      // 0..31 (256 cols)
    const int bm   = blockIdx.y;      // 0..15 (256 rows)

    const int pm0 = (wave & 1) * 8;   // A panel base (8 panels = 128 rows)
    const int pn0 = (wave >> 1) * 8;  // B panel base (8 panels = 128 cols)

    // staging: wave w stages A panels {4w..4w+3} and B panels {4w..4w+3}
    const unsigned char* ag[4];
    const unsigned char* bg[4];
    int slo[4];
#pragma unroll
    for (int r = 0; r < 4; ++r) {
        const int p = 4 * wave + r;
        ag[r]  = Ap + (size_t)(bm * 16 + p) * 65536 + lane * 16;
        bg[r]  = Bp + (size_t)(bn * 16 + p) * 65536 + lane * 16;
        slo[r] = p * 1024;  // wave-uniform; HW adds lane*16
    }

    const int a_off = pm0 * 1024 + lane * 16;  // + i*1024
    const int b_off = pn0 * 1024 + lane * 16;  // + j*1024

    int4v acc[8][8];
#pragma unroll
    for (int i = 0; i < 8; ++i)
#pragma unroll
        for (int j = 0; j < 8; ++j) acc[i][j] = (int4v)0;

    const int NT = K_DIM / 64;  // 64

    // prologue: stage T=0 -> buf0, T=1 -> buf1
#pragma unroll
    for (int r = 0; r < 4; ++r) {
        async_copy16(ag[r], As + slo[r]);
        async_copy16(bg[r], Bs + slo[r]);
        async_copy16(ag[r] + 1024, As + 16384 + slo[r]);
        async_copy16(bg[r] + 1024, Bs + 16384 + slo[r]);
    }
    __syncthreads();

    // fragment register double-buffer; load T=0 into set 0
    int4v afr[2][8], bfr[2][8];
#pragma unroll
    for (int i = 0; i < 8; ++i) afr[0][i] = *(const int4v*)(As + a_off + i * 1024);
#pragma unroll
    for (int j = 0; j < 8; ++j) bfr[0][j] = *(const int4v*)(Bs + b_off + j * 1024);

#pragma unroll 2
    for (int T = 0; T < NT; ++T) {
        const int cs = T & 1;
        const int ns = cs ^ 1;

        // stage T+2 (drained at this iter's barrier, consumed at T+2)
        if (T + 2 < NT) {
            const size_t gko = (size_t)(T + 2) * 1024;
            const int buf = ((T + 2) & 3) * 16384;
#pragma unroll
            for (int r = 0; r < 4; ++r) {
                async_copy16(ag[r] + gko, As + buf + slo[r]);
                async_copy16(bg[r] + gko, Bs + buf + slo[r]);
            }
        }

        // prefetch T+1 fragments into the ALTERNATE register set.
        // Buffer (T+1)&3 was staged at iter T-1 and drained at T-1's barrier.
        if (T + 1 < NT) {
            const int nb = ((T + 1) & 3) * 16384;
#pragma unroll
            for (int i = 0; i < 8; ++i)
                afr[ns][i] = *(const int4v*)(As + nb + a_off + i * 1024);
#pragma unroll
            for (int j = 0; j < 8; ++j)
                bfr[ns][j] = *(const int4v*)(Bs + nb + b_off + j * 1024);
        }

        // 64 independent MFMAs on set cs — no dependence on the reads above
#pragma unroll
        for (int i = 0; i < 8; ++i)
#pragma unroll
            for (int j = 0; j < 8; ++j)
                acc[i][j] = __builtin_amdgcn_mfma_i32_16x16x64_i8(afr[cs][i], bfr[cs][j],
                                                                  acc[i][j], 0, 0, 0);

        __syncthreads();
    }

    // --- epilogue: C/D layout col=lane&15, row=(lane>>4)*4+reg (verified)
    const int gcol0 = bn * 256 + pn0 * 16 + (lane & 15);
    float ac8[8];
#pragma unroll
    for (int j = 0; j < 8; ++j) ac8[j] = (float)acol[gcol0 + j * 16];

    const size_t grow0 = (size_t)bm * 256 + pm0 * 16 + (lane >> 4) * 4;
#pragma unroll
    for (int i = 0; i < 8; ++i) {
#pragma unroll
        for (int r = 0; r < 4; ++r) {
            const size_t row = grow0 + i * 16 + r;
            const float ar = (float)arow[row];
            _Float16* outp = Cout + row * (size_t)N_DIM + gcol0;
#pragma unroll
            for (int j = 0; j < 8; ++j) {
                float v = (float)acc[i][j][r] * ar * ac8[j];
                outp[j * 16] = (_Float16)v;
            }
        }
    }
}

// ---------------------------------------------------------------------------
extern "C" void kernel_launch(void* const* d_in, const int* in_sizes, int n_in,
                              void* d_out, int out_size, void* d_ws, size_t ws_size,
                              hipStream_t stream) {
    const int* a = (const int*)d_in[0];             // [M,K] int32 (int8 values)
    const int* b = (const int*)d_in[1];             // [N,K] int32 (int8 values)
    const _Float16* ar = (const _Float16*)d_in[2];  // [M] fp16
    const _Float16* ac = (const _Float16*)d_in[3];  // [N] fp16
    _Float16* out = (_Float16*)d_out;               // [M,N] fp16

    unsigned char* pa = (unsigned char*)d_ws;        // 16 MB
    unsigned char* pb = pa + (size_t)M_DIM * K_DIM;  // 32 MB

    const size_t total_frag = (size_t)(M_DIM / 16 + N_DIM / 16) * (K_DIM / 64) * 64;
    pack_frag<<<(int)(total_frag / 256), 256, 0, stream>>>(a, b, pa, pb);

    dim3 grid(N_DIM / 256, M_DIM / 256);
    gemm_i8<<<grid, 256, 0, stream>>>(pa, pb, ar, ac, out);
}

// Round 10
// 381.671 us; speedup vs baseline: 2.1745x; 2.1745x over previous
//
#include <hip/hip_runtime.h>
#include <cstdint>
#include <cstddef>

#define M_DIM 4096
#define N_DIM 8192
#define K_DIM 4096

typedef __attribute__((ext_vector_type(4))) int int4v;
typedef __attribute__((ext_vector_type(16))) int int16v;

// ---------------------------------------------------------------------------
// Pack int32 -> int8 in 32x32x32-i8 MFMA fragment order.
// p = 32-row panel, s = 32-byte kstep. chunk(p,s) = 1024 B where lane l
// holds row 32p+(l&31), k-bytes s*32 + (l>>5)*16 .. +16.
// Panel stride = 32*K = 131072 B; within panel, ksteps contiguous (1024 B).
// One thread = one 16-B lane-fragment: 4x dwordx4 reads, 16-B coalesced write.
// ---------------------------------------------------------------------------
__global__ void __launch_bounds__(256) pack_frag(const int* __restrict__ a,
                                                 const int* __restrict__ b,
                                                 unsigned char* __restrict__ pa,
                                                 unsigned char* __restrict__ pb) {
    size_t t = (size_t)blockIdx.x * 256 + threadIdx.x;
    const size_t NA = (size_t)(M_DIM / 32) * (K_DIM / 32) * 64;
    const int* __restrict__ src;
    unsigned char* __restrict__ dst;
    if (t < NA) {
        src = a; dst = pa;
    } else {
        src = b; dst = pb; t -= NA;
    }
    const int l = (int)(t & 63);
    const int s = (int)((t >> 6) & (K_DIM / 32 - 1));  // 0..127
    const int p = (int)(t >> 13);
    const int* g = src + ((size_t)(32 * p + (l & 31))) * K_DIM + s * 32 + (l >> 5) * 16;
    const int4v* g4 = (const int4v*)g;
    int4v o;
#pragma unroll
    for (int q = 0; q < 4; ++q) {
        int4v v = g4[q];
        o[q] = (v[0] & 0xff) | ((v[1] & 0xff) << 8) | ((v[2] & 0xff) << 16) | (v[3] << 24);
    }
    ((int4v*)dst)[t] = o;
}

// ---------------------------------------------------------------------------
// GEMM: block 256x256, 512 thr = 8 waves (2 waves/SIMD), wave tile 64x128
// = 2 A-panels x 4 B-panels of 32, mfma_i32_32x32x32_i8 (16 MFMA/iter/wave).
// vs R8 (16x16x64): 2x MACs per fragment byte -> LDS reads halve
// (96->48 KB/block-iter), MFMA inst count halves; matrix-pipe time same.
// Quad-buffered LDS (4 x 32 KB), ONE barrier per TWO K-iters (R8 structure).
// VGPR ~190: no spills (R9 lesson: 256 is the hard cap).
// ---------------------------------------------------------------------------
__device__ inline void async_copy16(const unsigned char* g, unsigned char* l) {
    __builtin_amdgcn_global_load_lds(
        (const __attribute__((address_space(1))) void*)g,
        (__attribute__((address_space(3))) void*)l,
        16, 0, 0);
}

__global__ void __launch_bounds__(512, 2) gemm_i8(const unsigned char* __restrict__ Ap,
                                                  const unsigned char* __restrict__ Bp,
                                                  const _Float16* __restrict__ arow,
                                                  const _Float16* __restrict__ acol,
                                                  _Float16* __restrict__ Cout) {
    __shared__ __align__(16) unsigned char As[4 * 16384];
    __shared__ __align__(16) unsigned char Bs[4 * 16384];

    const int tid  = threadIdx.x;
    const int lane = tid & 63;
    const int wave = tid >> 6;        // 0..7
    const int bn   = blockIdx.x;      // 0..31 (256 cols)
    const int bm   = blockIdx.y;      // 0..15 (256 rows)

    const int pm0 = (wave & 3) * 2;   // A panel base (2 panels of 32 = 64 rows)
    const int pn0 = (wave >> 2) * 4;  // B panel base (4 panels of 32 = 128 cols)

    // staging: wave w stages A panel w and B panel w (8 panels each).
    // Global chunk (panel p, kstep s): base + p*131072 + s*1024 + lane*16.
    const unsigned char* ag = Ap + (size_t)(bm * 8 + wave) * 131072 + lane * 16;
    const unsigned char* bg = Bp + (size_t)(bn * 8 + wave) * 131072 + lane * 16;
    const int slo = wave * 2048;  // wave-uniform LDS offset; HW adds lane*16

    const int a_off = pm0 * 2048 + lane * 16;  // + i*2048 + u*1024
    const int b_off = pn0 * 2048 + lane * 16;  // + j*2048 + u*1024

    int16v acc[2][4];
#pragma unroll
    for (int i = 0; i < 2; ++i)
#pragma unroll
        for (int j = 0; j < 4; ++j) acc[i][j] = (int16v)0;

    const int NT = K_DIM / 64;  // 64 iters, BK=64 (2 ksteps of 32)

    // prologue: stage T=0 -> buf0, T=1 -> buf1  (each: 2 ksteps A + 2 B)
#pragma unroll
    for (int u = 0; u < 2; ++u) {
        async_copy16(ag + u * 1024,        As + slo + u * 1024);
        async_copy16(bg + u * 1024,        Bs + slo + u * 1024);
        async_copy16(ag + 2048 + u * 1024, As + 16384 + slo + u * 1024);
        async_copy16(bg + 2048 + u * 1024, Bs + 16384 + slo + u * 1024);
    }
    __syncthreads();

    for (int T = 0; T < NT; T += 2) {
        // stage T+2, T+3 (drained at the barrier below, after two compute iters)
        if (T + 2 < NT) {
#pragma unroll
            for (int w = 2; w < 4; ++w) {
                const size_t gko = (size_t)(T + w) * 2048;
                const int buf = ((T + w) & 3) * 16384;
#pragma unroll
                for (int u = 0; u < 2; ++u) {
                    async_copy16(ag + gko + u * 1024, As + buf + slo + u * 1024);
                    async_copy16(bg + gko + u * 1024, Bs + buf + slo + u * 1024);
                }
            }
        }

        // two compute iterations; bulk reads, compiler-scheduled
#pragma unroll
        for (int v = 0; v < 2; ++v) {
            const int cur = ((T + v) & 3) * 16384;
            const unsigned char* Ac = As + cur;
            const unsigned char* Bc = Bs + cur;

            int4v af[2][2], bf[2][4];
#pragma unroll
            for (int u = 0; u < 2; ++u) {
#pragma unroll
                for (int i = 0; i < 2; ++i)
                    af[u][i] = *(const int4v*)(Ac + a_off + i * 2048 + u * 1024);
#pragma unroll
                for (int j = 0; j < 4; ++j)
                    bf[u][j] = *(const int4v*)(Bc + b_off + j * 2048 + u * 1024);
            }

#pragma unroll
            for (int u = 0; u < 2; ++u)
#pragma unroll
                for (int i = 0; i < 2; ++i)
#pragma unroll
                    for (int j = 0; j < 4; ++j)
                        acc[i][j] = __builtin_amdgcn_mfma_i32_32x32x32_i8(
                            af[u][i], bf[u][j], acc[i][j], 0, 0, 0);
        }

        __syncthreads();
    }

    // --- epilogue: 32x32 C/D layout (verified m74/m101):
    // col = lane&31, row = (reg&3) + 8*(reg>>2) + 4*(lane>>5)
    const int gcol0 = bn * 256 + pn0 * 32 + (lane & 31);
    float ac4[4];
#pragma unroll
    for (int j = 0; j < 4; ++j) ac4[j] = (float)acol[gcol0 + j * 32];

    const size_t rbase = (size_t)bm * 256 + pm0 * 32 + 4 * (lane >> 5);
#pragma unroll
    for (int i = 0; i < 2; ++i) {
#pragma unroll
        for (int r = 0; r < 16; ++r) {
            const size_t row = rbase + i * 32 + (r & 3) + 8 * (r >> 2);
            const float ar = (float)arow[row];
            _Float16* outp = Cout + row * (size_t)N_DIM + gcol0;
#pragma unroll
            for (int j = 0; j < 4; ++j) {
                float v = (float)acc[i][j][r] * ar * ac4[j];
                outp[j * 32] = (_Float16)v;
            }
        }
    }
}

// ---------------------------------------------------------------------------
extern "C" void kernel_launch(void* const* d_in, const int* in_sizes, int n_in,
                              void* d_out, int out_size, void* d_ws, size_t ws_size,
                              hipStream_t stream) {
    const int* a = (const int*)d_in[0];             // [M,K] int32 (int8 values)
    const int* b = (const int*)d_in[1];             // [N,K] int32 (int8 values)
    const _Float16* ar = (const _Float16*)d_in[2];  // [M] fp16
    const _Float16* ac = (const _Float16*)d_in[3];  // [N] fp16
    _Float16* out = (_Float16*)d_out;               // [M,N] fp16

    unsigned char* pa = (unsigned char*)d_ws;        // 16 MB
    unsigned char* pb = pa + (size_t)M_DIM * K_DIM;  // 32 MB

    const size_t total_frag = (size_t)(M_DIM / 32 + N_DIM / 32) * (K_DIM / 32) * 64;
    pack_frag<<<(int)(total_frag / 256), 256, 0, stream>>>(a, b, pa, pb);

    dim3 grid(N_DIM / 256, M_DIM / 256);
    gemm_i8<<<grid, 512, 0, stream>>>(pa, pb, ar, ac, out);
}